// Round 9
// baseline (72.853 us; speedup 1.0000x reference)
//
#include <hip/hip_runtime.h>
#include <stdint.h>

#define BN_TOTAL 25600   // B*N = 256*100
#define DDIM 128
#define KN 16

typedef __bf16 bf16x8 __attribute__((ext_vector_type(8)));
typedef __bf16 bf16x4 __attribute__((ext_vector_type(4)));
typedef float f32x4 __attribute__((ext_vector_type(4)));
typedef float f32x16 __attribute__((ext_vector_type(16)));

__device__ __forceinline__ void gload_lds16(const void* g, void* l) {
    __builtin_amdgcn_global_load_lds(
        (const __attribute__((address_space(1))) void*)g,
        (__attribute__((address_space(3))) void*)l, 16, 0, 0);
}

// DPP rotate-add all-reduce within each 16-lane row (VALU pipe, no DS ops).
template<int CTRL>
__device__ __forceinline__ float rotadd(float v) {
    const int r = __builtin_amdgcn_mov_dpp(__builtin_bit_cast(int, v), CTRL, 0xF, 0xF, false);
    return v + __builtin_bit_cast(float, r);
}
__device__ __forceinline__ float allreduce16(float v) {
    v = rotadd<0x121>(v);   // row_ror:1
    v = rotadd<0x122>(v);   // row_ror:2
    v = rotadd<0x124>(v);   // row_ror:4
    v = rotadd<0x128>(v);   // row_ror:8
    return v;
}

// ---------------- Kernel 0: pre-build w1/w3 bf16 MFMA fragment images --------
// fw1: 32 slots (t*4+s) x 64 lanes of bf16x8 = 32 KB
// fw3: 64 slots (t*8+s) x 64 lanes of bf16x8 = 64 KB
__global__ __launch_bounds__(256) void k0_build_frags(
    const float* __restrict__ w1,   // [129,128]
    const float* __restrict__ w3,   // [256,128]
    bf16x8* __restrict__ fw1,
    bf16x8* __restrict__ fw3)
{
    const int slot = blockIdx.x * 256 + threadIdx.x;   // [0, 6144)
    if (slot < 2048) {
        const int idx  = slot >> 6;        // t*4+s
        const int lane = slot & 63;
        const int t = idx >> 2, s = idx & 3;
        const int grp = lane >> 4, lr = lane & 15;
        const int fbase = grp * 8 + 32 * s;
        const int d = t * 16 + lr;
        bf16x8 tmp;
        #pragma unroll
        for (int j = 0; j < 8; ++j)
            tmp[j] = (__bf16)w1[(fbase + j) * DDIM + d];
        fw1[slot] = tmp;
    } else {
        const int q = slot - 2048;         // [0, 4096)
        const int idx  = q >> 6;           // t*8+s
        const int lane = q & 63;
        const int t = idx >> 3, s = idx & 7;
        const int grp = lane >> 4, lr = lane & 15;
        const int fbase = grp * 8 + 32 * s;
        const int d = t * 16 + lr;
        bf16x8 tmp;
        #pragma unroll
        for (int j = 0; j < 8; ++j)
            tmp[j] = (__bf16)w3[(fbase + j) * DDIM + d];
        fw3[q] = tmp;
    }
}

// ---------------- Kernel 1: attention + aggregation -> agg bf16 [BN][128] ----
// One wave per (b,n). 3200 blocks x 8 waves. DS-pipe-lean softmax: DPP
// rotate-reduce (VALU), alpha broadcast via 32B LDS scratch, fused f2 weights.
__global__ __launch_bounds__(512, 6) void k1_attn_agg(
    const float* __restrict__ nbr,    // [BN,16,128]
    const float* __restrict__ wgt,    // [BN,16]
    const float* __restrict__ extra,  // [BN,128]
    const float* __restrict__ w1,     // [129,128]
    const float* __restrict__ w2,     // [128]
    const bf16x8* __restrict__ fw1,   // prebuilt fragments
    unsigned short* __restrict__ aggb)// [BN,128] bf16
{
    __shared__ bf16x8 b1frag[32][64];                     // 32 KB
    __shared__ float2 wlw2[DDIM];                         // 1 KB {w1[128][d], w2[d]}
    __shared__ __align__(16) unsigned short alds[8][16];  // 256 B alpha scratch

    const int tid  = threadIdx.x;
    const int lane = tid & 63;
    const int wave = tid >> 6;    // 0..7
    const int grp  = lane >> 4;   // 0..3
    const int lr   = lane & 15;   // 0..15
    const int half = lane >> 5;   // 0..1  (32x32 MFMA)
    const int col  = lane & 31;   // 0..31 (32x32 MFMA)

    // stage prebuilt w1 fragments: wave w loads slots w*4 .. w*4+3
    #pragma unroll
    for (int c = 0; c < 4; ++c)
        gload_lds16(fw1 + (wave * 4 + c) * 64 + lane, &b1frag[wave * 4 + c][0]);
    if (tid < DDIM)
        wlw2[tid] = make_float2(w1[DDIM * DDIM + tid], w2[tid]);
    __syncthreads();

    const int bn = blockIdx.x * 8 + wave;
    const float* nb = nbr   + (size_t)bn * (KN * DDIM);
    const float* ex = extra + (size_t)bn * DDIM;

    // acc init = weight[r] * w1[128][d]; w2 column kept in regs for the dot.
    const float4 wv = *(const float4*)(wgt + (size_t)bn * KN + grp * 4);
    float w2v[8];
    f32x4 acc[8];
    #pragma unroll
    for (int t = 0; t < 8; ++t) {
        const float2 ww = wlw2[t * 16 + lr];   // one ds_read_b64
        w2v[t] = ww.y;
        acc[t][0] = wv.x * ww.x;
        acc[t][1] = wv.y * ww.x;
        acc[t][2] = wv.z * ww.x;
        acc[t][3] = wv.w * ww.x;
    }

    // ---- stage 1: h = feat @ w1  (A-frags from global, B-frags from LDS)
    #pragma unroll
    for (int s = 0; s < 4; ++s) {
        const int f0 = grp * 8 + 32 * s;
        const float4 n0 = *(const float4*)(nb + lr * DDIM + f0);
        const float4 n1 = *(const float4*)(nb + lr * DDIM + f0 + 4);
        const float4 e0 = *(const float4*)(ex + f0);
        const float4 e1 = *(const float4*)(ex + f0 + 4);
        bf16x8 af;
        af[0] = (__bf16)(n0.x * e0.x); af[1] = (__bf16)(n0.y * e0.y);
        af[2] = (__bf16)(n0.z * e0.z); af[3] = (__bf16)(n0.w * e0.w);
        af[4] = (__bf16)(n1.x * e1.x); af[5] = (__bf16)(n1.y * e1.y);
        af[6] = (__bf16)(n1.z * e1.z); af[7] = (__bf16)(n1.w * e1.w);
        #pragma unroll
        for (int t = 0; t < 8; ++t)
            acc[t] = __builtin_amdgcn_mfma_f32_16x16x32_bf16(
                         af, b1frag[t * 4 + s][lane], acc[t], 0, 0, 0);
    }

    // ---- issue stage-2 B loads now (tile L1/L2-hot); consumed after softmax,
    // latency hides under the reduce/exp chain.
    // lane needs nbr[k = half*8+j][f = t*32+col]
    bf16x8 b2f[4];
    #pragma unroll
    for (int t = 0; t < 4; ++t)
        #pragma unroll
        for (int j = 0; j < 8; ++j)
            b2f[t][j] = (__bf16)nb[(half * 8 + j) * DDIM + t * 32 + col];

    // ---- leaky_relu(0.2) + dot with w2 -> logits for rows grp*4+r
    float sum0 = 0.f, sum1 = 0.f, sum2 = 0.f, sum3 = 0.f;
    #pragma unroll
    for (int t = 0; t < 8; ++t) {
        float h;
        h = acc[t][0]; h = fmaxf(h, 0.2f * h); sum0 = fmaf(h, w2v[t], sum0);
        h = acc[t][1]; h = fmaxf(h, 0.2f * h); sum1 = fmaf(h, w2v[t], sum1);
        h = acc[t][2]; h = fmaxf(h, 0.2f * h); sum2 = fmaf(h, w2v[t], sum2);
        h = acc[t][3]; h = fmaxf(h, 0.2f * h); sum3 = fmaf(h, w2v[t], sum3);
    }
    // 16-lane all-reduce on the VALU pipe (DPP), not the DS pipe.
    sum0 = allreduce16(sum0);
    sum1 = allreduce16(sum1);
    sum2 = allreduce16(sum2);
    sum3 = allreduce16(sum3);

    // softmax over the 16 rows (group g holds rows 4g..4g+3, replicated)
    float mx = fmaxf(fmaxf(sum0, sum1), fmaxf(sum2, sum3));
    mx = fmaxf(mx, __shfl_xor(mx, 16, 64));
    mx = fmaxf(mx, __shfl_xor(mx, 32, 64));
    const float ev0 = __expf(sum0 - mx);
    const float ev1 = __expf(sum1 - mx);
    const float ev2 = __expf(sum2 - mx);
    const float ev3 = __expf(sum3 - mx);
    float es = ev0 + ev1 + ev2 + ev3;
    es += __shfl_xor(es, 16, 64);
    es += __shfl_xor(es, 32, 64);
    const float inv = 1.0f / es;

    // ---- alpha broadcast through 32B per-wave LDS scratch:
    // group leaders write alpha[4g..4g+3] as bf16 (1 ds_write_b64), every lane
    // reads its A2 fragment (k = half*8 .. half*8+7) with 1 ds_read_b128.
    if (lr == 0) {
        bf16x4 av;
        av[0] = (__bf16)(ev0 * inv);
        av[1] = (__bf16)(ev1 * inv);
        av[2] = (__bf16)(ev2 * inv);
        av[3] = (__bf16)(ev3 * inv);
        *(bf16x4*)&alds[wave][grp * 4] = av;
    }
    const bf16x8 a2 = *(const bf16x8*)&alds[wave][half * 8];

    // ---- agg = alpha^T @ nbr via 4x mfma_32x32x16. All C rows identical
    // (= agg), so every lane's r[0] = agg[t*32+col]; half-waves split tiles.
    f32x16 z;
    #pragma unroll
    for (int i = 0; i < 16; ++i) z[i] = 0.f;

    unsigned short* ao = aggb + (size_t)bn * DDIM;
    #pragma unroll
    for (int t = 0; t < 4; ++t) {
        const f32x16 r = __builtin_amdgcn_mfma_f32_32x32x16_bf16(a2, b2f[t], z, 0, 0, 0);
        if ((t >> 1) == half) {
            const __bf16 rb = (__bf16)r[0];
            ao[t * 32 + col] = __builtin_bit_cast(unsigned short, rb);
        }
    }
}

// ---------------- Kernel 2: out = relu([self | agg] @ w3) -------------------
// 200 blocks x 8 waves (512 thr), 128 rows/block — single generation.
__global__ __launch_bounds__(512, 4) void k2_out_gemm(
    const float* __restrict__ selfv,          // [BN,128] f32
    const unsigned short* __restrict__ aggb,  // [BN,128] bf16
    const bf16x8* __restrict__ fw3,           // prebuilt fragments
    float* __restrict__ out)                  // [BN,128]
{
    __shared__ bf16x8 w3frag[64][64];  // 64 KB

    const int tid  = threadIdx.x;
    const int lane = tid & 63;
    const int wave = tid >> 6;    // 0..7
    const int grp  = lane >> 4;
    const int lr   = lane & 15;

    #pragma unroll
    for (int c = 0; c < 8; ++c)
        gload_lds16(fw3 + (wave * 8 + c) * 64 + lane, &w3frag[wave * 8 + c][0]);
    __syncthreads();

    const int rowbase = blockIdx.x * 128 + wave * 16;
    const int row = rowbase + lr;

    f32x4 acc[8];
    #pragma unroll
    for (int t = 0; t < 8; ++t) {
        acc[t][0] = 0.f; acc[t][1] = 0.f; acc[t][2] = 0.f; acc[t][3] = 0.f;
    }

    #pragma unroll
    for (int s = 0; s < 8; ++s) {
        bf16x8 af;
        if (s < 4) {
            const int f0 = grp * 8 + 32 * s;
            const float4 x0 = *(const float4*)(selfv + (size_t)row * DDIM + f0);
            const float4 x1 = *(const float4*)(selfv + (size_t)row * DDIM + f0 + 4);
            af[0] = (__bf16)x0.x; af[1] = (__bf16)x0.y;
            af[2] = (__bf16)x0.z; af[3] = (__bf16)x0.w;
            af[4] = (__bf16)x1.x; af[5] = (__bf16)x1.y;
            af[6] = (__bf16)x1.z; af[7] = (__bf16)x1.w;
        } else {
            const int f0 = grp * 8 + 32 * (s - 4);
            af = *(const bf16x8*)(aggb + (size_t)row * DDIM + f0);
        }
        #pragma unroll
        for (int t = 0; t < 8; ++t)
            acc[t] = __builtin_amdgcn_mfma_f32_16x16x32_bf16(
                         af, w3frag[t * 8 + s][lane], acc[t], 0, 0, 0);
    }

    #pragma unroll
    for (int t = 0; t < 8; ++t) {
        #pragma unroll
        for (int j = 0; j < 4; ++j) {
            const int r = rowbase + grp * 4 + j;
            out[(size_t)r * DDIM + t * 16 + lr] = fmaxf(acc[t][j], 0.0f);
        }
    }
}

extern "C" void kernel_launch(void* const* d_in, const int* in_sizes, int n_in,
                              void* d_out, int out_size, void* d_ws, size_t ws_size,
                              hipStream_t stream)
{
    const float* selfv = (const float*)d_in[0];
    const float* nbr   = (const float*)d_in[1];
    const float* wgt   = (const float*)d_in[2];
    const float* extra = (const float*)d_in[3];
    const float* w1    = (const float*)d_in[4];
    const float* w2    = (const float*)d_in[5];
    const float* w3    = (const float*)d_in[6];
    float* out = (float*)d_out;

    // workspace layout: agg bf16 (6.55 MB) | fw1 @ 8 MB (32 KB) | fw3 @ +128 KB (64 KB)
    unsigned short* aggb = (unsigned short*)d_ws;
    bf16x8* fw1 = (bf16x8*)((char*)d_ws + (8u << 20));
    bf16x8* fw3 = (bf16x8*)((char*)d_ws + (8u << 20) + (128u << 10));

    hipLaunchKernelGGL(k0_build_frags, dim3(24), dim3(256), 0, stream, w1, w3, fw1, fw3);
    // 3200 blocks * 8 waves = 25600 bn
    hipLaunchKernelGGL(k1_attn_agg, dim3(3200), dim3(512), 0, stream,
                       nbr, wgt, extra, w1, w2, fw1, aggb);
    // 200 blocks * 128 rows = 25600 rows
    hipLaunchKernelGGL(k2_out_gemm, dim3(200), dim3(512), 0, stream,
                       selfv, aggb, fw3, out);
}